// Round 8
// baseline (229.975 us; speedup 1.0000x reference)
//
#include <hip/hip_runtime.h>

#define S 48
#define T 16
#define NTOT (2 * S * S * S * T) // 3,538,944
#define NBLK (2 * S * S)         // 4608 blocks: one per (b,y,x) z-column
#define NSLOT 64                 // atomic slots, one cacheline (64B = 16 floats) apart

using f4 = __attribute__((ext_vector_type(4))) float;

// ---- torch.gradient first derivative along an axis, unit spacing ----
__device__ __forceinline__ float d1(const float* __restrict__ fc, int i, int N, int stride) {
    int dl = (i > 0) ? -stride : 0;
    int dr = (i < N - 1) ? stride : 0;
    float w = (i > 0 && i < N - 1) ? 0.5f : 1.0f;
    return (fc[dr] - fc[dl]) * w;
}

// ---- composed gradient-of-gradient (the reference's lap terms), generic ----
//  i==0   : 0.5 f0 - f1 + 0.5 f2
//  i==1   : 0.5 f0 - 0.75 f1 + 0.25 f3
//  inner  : 0.25 (f[i-2] - 2 f[i] + f[i+2])
//  i==N-2 : 0.25 f[N-4] - 0.75 f[N-2] + 0.5 f[N-1]
//  i==N-1 : 0.5 f[N-3] - f[N-2] + 0.5 f[N-1]
__device__ __forceinline__ float d2c(const float* __restrict__ fc, int i, int N, int stride) {
    int j0, j1, j2;
    float c0, c1, c2;
    if (i == 0)          { j0 = 0;  j1 = 1;  j2 = 2; c0 = 0.5f;  c1 = -1.0f;  c2 = 0.5f;  }
    else if (i == 1)     { j0 = -1; j1 = 0;  j2 = 2; c0 = 0.5f;  c1 = -0.75f; c2 = 0.25f; }
    else if (i == N - 1) { j0 = -2; j1 = -1; j2 = 0; c0 = 0.5f;  c1 = -1.0f;  c2 = 0.5f;  }
    else if (i == N - 2) { j0 = -2; j1 = 0;  j2 = 1; c0 = 0.25f; c1 = -0.75f; c2 = 0.5f;  }
    else                 { j0 = -2; j1 = 0;  j2 = 2; c0 = 0.25f; c1 = -0.5f;  c2 = 0.25f; }
    return c0 * fc[j0 * stride] + c1 * fc[j1 * stride] + c2 * fc[j2 * stride];
}

// Interior-only gradient-of-gradient; center value supplied from a register
// (already loaded from LDS) -> only 2 global taps instead of 3.
__device__ __forceinline__ float d2c_i(const float* __restrict__ fc, float center, int stride) {
    return 0.25f * (fc[-2 * stride] + fc[2 * stride]) - 0.5f * center;
}

// Element strides:
//   V/F (B,S,S,S,3,T): z: 48, x: 2304, y: 110592; channel: 16 (ch0=Vy, ch1=Vx, ch2=Vz)
//   P/Y/X/X1/C (B,S,S,S,T): z: 16, x: 768, y: 36864
//
// R8 design: block = one (b,y,x) z-column (48z x 16t = 768 elems, 3/thread).
// V(3ch)+P+Y column staged in LDS (15 KB) -> all z-taps, t-taps and centers
// served by ds_read; only x/y taps + streaming arrays hit global (~34 vs 68
// loads/elem). x/y interior selection is BLOCK-uniform (x,y fixed per block).
// Lessons kept: no forced launch_bounds cap (r3/r6 spills), 64-slot atomics (r4).
__global__ __launch_bounds__(256) void fused_loss(
    const float* __restrict__ Cmat, const float* __restrict__ V,
    const float* __restrict__ P, const float* __restrict__ Xa,
    const float* __restrict__ X1a, const float* __restrict__ F,
    const float* __restrict__ Rep, const float* __restrict__ Xlast,
    const float* __restrict__ Y, float* __restrict__ ws)
{
    const int bidx = blockIdx.x;
    const int x = bidx % S;
    const int y = (bidx / S) % S;
    const int b = bidx / (S * S);
    const int sp0 = ((b * S + y) * S + x) * S; // spatial index at z=0
    const int n0 = sp0 * T;                    // base into (B,S,S,S,T) arrays
    const int v0 = sp0 * 48;                   // base into (B,S,S,S,3,T) arrays

    __shared__ float sV[3][S][T]; // 9 KB
    __shared__ float sP[S][T];    // 3 KB
    __shared__ float sY[S][T];    // 3 KB

    const int tid = threadIdx.x;

    // ---- stage the column: 5 planes x 192 vec4 loads, fully coalesced ----
    for (int j = tid; j < 5 * 192; j += 256) {
        const int a  = j / 192;      // 0..2: V channel, 3: P, 4: Y
        const int r  = j % 192;
        const int z  = r >> 2;
        const int t4 = (r & 3) << 2;
        const float* src;
        float* dst;
        if (a < 3)       { src = V + v0 + z * 48 + a * 16 + t4; dst = &sV[a][z][t4]; }
        else if (a == 3) { src = P + n0 + z * 16 + t4;          dst = &sP[z][t4]; }
        else             { src = Y + n0 + z * 16 + t4;          dst = &sY[z][t4]; }
        *reinterpret_cast<f4*>(dst) = *reinterpret_cast<const f4*>(src);
    }
    __syncthreads();

    const float re = Rep[0];
    const bool xint = (x >= 2 && x < S - 2); // block-uniform
    const bool yint = (y >= 2 && y < S - 2); // block-uniform

    float am1 = 0.f, am2 = 0.f, aphy = 0.f, at1 = 0.f, at2 = 0.f;

    #pragma unroll 1
    for (int i = tid; i < S * T; i += 256) {
        const int z = i >> 4;
        const int t = i & 15;
        const int n = n0 + i;            // i == z*16 + t
        const int vb = v0 + z * 48 + t;

        // ---- elementwise losses (Y from LDS) ----
        const float yv  = sY[z][t];
        const float dm1 = X1a[n] - yv;
        const float dm2 = Xa[n] - yv;
        am1 += dm1 * dm1;
        am2 += dm2 * dm2;
        const float yprev = (t == 0) ? Xlast[sp0 + z] : sY[z][t - 1];
        const float dt1 = yprev - yv;
        const float dt2 = Cmat[n] - yv;
        at1 += dt1 * dt1;
        at2 += dt2 * dt2;

        // ---- physics ----
        const float vy = sV[0][z][t], vx = sV[1][z][t], vz = sV[2][z][t];
        float div;

        // channel 0 = Vy -> e1 (dPdy, Fy); contributes dVydy to divergence
        {
            const float* c = &sV[0][z][t];           // LDS: center, t-, z-taps
            const float ddt = d1(c, t, T, 1);
            const float ddz = d1(c, z, S, T);
            const float lz  = d2c(c, z, S, T);
            const float* g = V + vb;                 // global: x,y taps
            const float ddx = d1(g, x, S, 2304);
            const float ddy = d1(g, y, S, 110592);
            const float lx = xint ? d2c_i(g, vy, 2304)   : d2c(g, x, S, 2304);
            const float ly = yint ? d2c_i(g, vy, 110592) : d2c(g, y, S, 110592);
            const float dPdy = d1(P + n, y, S, 36864);
            const float e1 = ddt + (vx * ddx + vy * ddy + vz * ddz + dPdy)
                             - re * (lz + lx + ly) + F[vb];
            aphy += e1 * e1;
            div = ddy;
        }
        // channel 1 = Vx -> e2 (dPdx, Fx); contributes dVxdx
        {
            const float* c = &sV[1][z][t];
            const float ddt = d1(c, t, T, 1);
            const float ddz = d1(c, z, S, T);
            const float lz  = d2c(c, z, S, T);
            const float* g = V + vb + 16;
            const float ddx = d1(g, x, S, 2304);
            const float ddy = d1(g, y, S, 110592);
            const float lx = xint ? d2c_i(g, vx, 2304)   : d2c(g, x, S, 2304);
            const float ly = yint ? d2c_i(g, vx, 110592) : d2c(g, y, S, 110592);
            const float dPdx = d1(P + n, x, S, 768);
            const float e2 = ddt + (vx * ddx + vy * ddy + vz * ddz + dPdx)
                             - re * (lz + lx + ly) + F[vb + 16];
            aphy += e2 * e2;
            div += ddx;
        }
        // channel 2 = Vz -> e3 (dPdz, Fz); contributes dVzdz
        {
            const float* c = &sV[2][z][t];
            const float ddt = d1(c, t, T, 1);
            const float ddz = d1(c, z, S, T);
            const float lz  = d2c(c, z, S, T);
            const float* g = V + vb + 32;
            const float ddx = d1(g, x, S, 2304);
            const float ddy = d1(g, y, S, 110592);
            const float lx = xint ? d2c_i(g, vz, 2304)   : d2c(g, x, S, 2304);
            const float ly = yint ? d2c_i(g, vz, 110592) : d2c(g, y, S, 110592);
            const float dPdz = d1(&sP[z][t], z, S, T);   // from LDS
            const float e3 = ddt + (vx * ddx + vy * ddy + vz * ddz + dPdz)
                             - re * (lz + lx + ly) + F[vb + 32];
            aphy += e3 * e3;
            div += ddz;                                  // e4 = dVxdx+dVydy+dVzdz
            aphy += div * div;
        }
    }

    // ---- reduction: wave shuffle -> LDS -> 5 atomics to a cacheline-spread slot ----
    #pragma unroll
    for (int off = 32; off > 0; off >>= 1) {
        am1  += __shfl_down(am1, off);
        am2  += __shfl_down(am2, off);
        aphy += __shfl_down(aphy, off);
        at1  += __shfl_down(at1, off);
        at2  += __shfl_down(at2, off);
    }
    __shared__ float sred[4][5];
    const int lane = tid & 63;
    const int wv   = tid >> 6;
    if (lane == 0) {
        sred[wv][0] = am1; sred[wv][1] = am2; sred[wv][2] = aphy;
        sred[wv][3] = at1; sred[wv][4] = at2;
    }
    __syncthreads();
    if (tid == 0) {
        float s0 = 0.f, s1 = 0.f, s2 = 0.f, s3 = 0.f, s4 = 0.f;
        #pragma unroll
        for (int w = 0; w < 4; ++w) {
            s0 += sred[w][0]; s1 += sred[w][1]; s2 += sred[w][2];
            s3 += sred[w][3]; s4 += sred[w][4];
        }
        float* slot = ws + (bidx & (NSLOT - 1)) * 16; // 64B apart
        atomicAdd(&slot[0], s0);
        atomicAdd(&slot[1], s1);
        atomicAdd(&slot[2], s2);
        atomicAdd(&slot[3], s3);
        atomicAdd(&slot[4], s4);
    }
}

// 64 threads: lane l sums slot l, then wave-shuffle combine.
__global__ void finalize_kernel(const float* __restrict__ ws, float* __restrict__ out) {
    const int l = threadIdx.x; // 0..63
    float s0 = ws[l * 16 + 0];
    float s1 = ws[l * 16 + 1];
    float s2 = ws[l * 16 + 2];
    float s3 = ws[l * 16 + 3];
    float s4 = ws[l * 16 + 4];
    #pragma unroll
    for (int off = 32; off > 0; off >>= 1) {
        s0 += __shfl_down(s0, off);
        s1 += __shfl_down(s1, off);
        s2 += __shfl_down(s2, off);
        s3 += __shfl_down(s3, off);
        s4 += __shfl_down(s4, off);
    }
    if (l == 0) {
        const float invN = 1.0f / (float)NTOT;
        const float m1  = s0 * invN;
        const float m2  = s1 * invN;
        const float phy = s2 * invN;
        const float t1  = s3 * invN;
        const float t2  = s4 * invN;
        out[0] = m1;
        out[1] = m2;
        out[2] = phy;
        out[3] = (t1 < t2) ? (t2 - t1) : 0.0f;
    }
}

extern "C" void kernel_launch(void* const* d_in, const int* in_sizes, int n_in,
                              void* d_out, int out_size, void* d_ws, size_t ws_size,
                              hipStream_t stream) {
    // setup_inputs order:
    // 0 C_all, 1 V_all, 2 P_all, 3 X_all, 4 X1_all, 5 F_all, 6 Re, 7 X_last,
    // 8 Y_data, 9 maskd0, 10 maskd1, 11 maskd2
    const float* Cmat  = (const float*)d_in[0];
    const float* V     = (const float*)d_in[1];
    const float* P     = (const float*)d_in[2];
    const float* Xa    = (const float*)d_in[3];
    const float* X1a   = (const float*)d_in[4];
    const float* F     = (const float*)d_in[5];
    const float* Rep   = (const float*)d_in[6];
    const float* Xlast = (const float*)d_in[7];
    const float* Y     = (const float*)d_in[8];

    float* ws  = (float*)d_ws;
    float* out = (float*)d_out;

    hipMemsetAsync(ws, 0, NSLOT * 16 * sizeof(float), stream); // 4 KB of slots
    fused_loss<<<NBLK, 256, 0, stream>>>(Cmat, V, P, Xa, X1a, F, Rep, Xlast, Y, ws);
    finalize_kernel<<<1, 64, 0, stream>>>(ws, out);
}

// Round 9
// 228.212 us; speedup vs baseline: 1.0077x; 1.0077x over previous
//
#include <hip/hip_runtime.h>

#define S 48
#define T 16
#define NTOT (2 * S * S * S * T) // 3,538,944
#define NBLK (2 * S * S)         // 4608 blocks: one per (b,y,x) z-column
#define NTHR 192                 // 3 waves; one f4-item (4 t) per thread
#define NSLOT 64                 // atomic slots, one cacheline apart

using f4 = __attribute__((ext_vector_type(4))) float;

__device__ __forceinline__ f4 ld4(const float* __restrict__ p) {
    return *reinterpret_cast<const f4*>(p); // 16B-aligned at all call sites
}
__device__ __forceinline__ float dot4(f4 a) { return (a[0] + a[1]) + (a[2] + a[3]); }

// ---- torch.gradient d/di along a SPATIAL axis, vec4 over t (ptr: LDS or global) ----
__device__ __forceinline__ f4 d1v(const float* __restrict__ fc, int i, int N, int stride) {
    const int dl = (i > 0) ? -stride : 0;
    const int dr = (i < N - 1) ? stride : 0;
    const float w = (i > 0 && i < N - 1) ? 0.5f : 1.0f;
    return (ld4(fc + dr) - ld4(fc + dl)) * w;
}

// ---- composed gradient-of-gradient, generic (edges), vec4 over t ----
//  i==0   : 0.5 f0 - f1 + 0.5 f2
//  i==1   : 0.5 f0 - 0.75 f1 + 0.25 f3
//  inner  : 0.25 (f[i-2] - 2 f[i] + f[i+2])
//  i==N-2 : 0.25 f[N-4] - 0.75 f[N-2] + 0.5 f[N-1]
//  i==N-1 : 0.5 f[N-3] - f[N-2] + 0.5 f[N-1]
__device__ __forceinline__ f4 d2cv(const float* __restrict__ fc, int i, int N, int stride) {
    int j0, j1, j2;
    float c0, c1, c2;
    if (i == 0)          { j0 = 0;  j1 = 1;  j2 = 2; c0 = 0.5f;  c1 = -1.0f;  c2 = 0.5f;  }
    else if (i == 1)     { j0 = -1; j1 = 0;  j2 = 2; c0 = 0.5f;  c1 = -0.75f; c2 = 0.25f; }
    else if (i == N - 1) { j0 = -2; j1 = -1; j2 = 0; c0 = 0.5f;  c1 = -1.0f;  c2 = 0.5f;  }
    else if (i == N - 2) { j0 = -2; j1 = 0;  j2 = 1; c0 = 0.25f; c1 = -0.75f; c2 = 0.5f;  }
    else                 { j0 = -2; j1 = 0;  j2 = 2; c0 = 0.25f; c1 = -0.5f;  c2 = 0.25f; }
    return c0 * ld4(fc + j0 * stride) + c1 * ld4(fc + j1 * stride) + c2 * ld4(fc + j2 * stride);
}

// ---- temporal derivative of the 4-pack [t4..t4+3]; row = LDS t-row pointer ----
__device__ __forceinline__ f4 dtv(const float* __restrict__ row, f4 c, int t4) {
    const float lf = (t4 > 0)     ? row[-1] : 0.f;
    const float rt = (t4 < T - 4) ? row[4]  : 0.f;
    f4 r;
    r[0] = (t4 == 0)     ? (c[1] - c[0]) : 0.5f * (c[1] - lf);
    r[1] = 0.5f * (c[2] - c[0]);
    r[2] = 0.5f * (c[3] - c[1]);
    r[3] = (t4 == T - 4) ? (c[3] - c[2]) : 0.5f * (rt - c[2]);
    return r;
}

// Element strides:
//   V/F (B,S,S,S,3,T): z: 48, x: 2304, y: 110592; channel: 16 (ch0=Vy, ch1=Vx, ch2=Vz)
//   P/Y/X/X1/C (B,S,S,S,T): z: 16, x: 768, y: 36864
//
// R9 design: R8's LDS backbone (z/t taps + centers from LDS -> short liveness)
// + vec4-over-t for ALL remaining global loads (1KB/wave-load -> 4x bytes in
// flight at the same outstanding-load count; R8 stalled at 2TB/s because 4B-
// dest scalar loads capped per-CU bytes in flight at ~the Little's-law edge).
// Unlike failed R2 (all-global f4, 152 VGPR): LDS serves z/t/center so the
// live set stays channel-scoped. 192 thr/block, 1 f4-item each, no loop.
__global__ __launch_bounds__(NTHR) void fused_loss(
    const float* __restrict__ Cmat, const float* __restrict__ V,
    const float* __restrict__ P, const float* __restrict__ Xa,
    const float* __restrict__ X1a, const float* __restrict__ F,
    const float* __restrict__ Rep, const float* __restrict__ Xlast,
    const float* __restrict__ Y, float* __restrict__ ws)
{
    const int bidx = blockIdx.x;
    const int x = bidx % S;
    const int y = (bidx / S) % S;
    const int b = bidx / (S * S);
    const int sp0 = ((b * S + y) * S + x) * S; // spatial index at z=0
    const int n0 = sp0 * T;                    // base into (B,S,S,S,T) arrays
    const int v0 = sp0 * 48;                   // base into (B,S,S,S,3,T) arrays

    __shared__ float sV[3][S][T]; // 9 KB
    __shared__ float sP[S][T];    // 3 KB

    const int tid = threadIdx.x;

    // ---- stage V(3ch)+P column: 4 planes x 192 f4, one f4 per thread per plane ----
    for (int j = tid; j < 4 * 192; j += NTHR) {
        const int a  = j / 192;      // 0..2: V channel, 3: P
        const int r  = j % 192;
        const int zz = r >> 2;
        const int tt = (r & 3) << 2;
        const float* src = (a < 3) ? (V + v0 + zz * 48 + a * 16 + tt)
                                   : (P + n0 + zz * 16 + tt);
        float* dst = (a < 3) ? &sV[a][zz][tt] : &sP[zz][tt];
        *reinterpret_cast<f4*>(dst) = ld4(src);
    }
    __syncthreads();

    const float re = Rep[0];
    const bool xi = (x >= 2 && x < S - 2); // block-uniform
    const bool yi = (y >= 2 && y < S - 2); // block-uniform

    const int z  = tid >> 2;
    const int t4 = (tid & 3) << 2;
    const int n4 = n0 + z * 16 + t4;
    const int vb = v0 + z * 48 + t4;

    // ---- elementwise losses (all f4 streaming) ----
    const f4 yv = ld4(Y + n4);
    f4 dm = ld4(X1a + n4) - yv;  float am1 = dot4(dm * dm);
    dm = ld4(Xa + n4) - yv;      float am2 = dot4(dm * dm);
    dm = ld4(Cmat + n4) - yv;    float at2 = dot4(dm * dm);
    f4 yp;
    yp[0] = (t4 == 0) ? Xlast[sp0 + z] : Y[n4 - 1];
    yp[1] = yv[0]; yp[2] = yv[1]; yp[3] = yv[2];
    dm = yp - yv;                float at1 = dot4(dm * dm);

    // ---- physics: channel-at-a-time, scalar accumulation ----
    const f4 cy = ld4(&sV[0][z][t4]);
    const f4 cx = ld4(&sV[1][z][t4]);
    const f4 cz = ld4(&sV[2][z][t4]);

    float sph = 0.f;
    f4 div;

    // channel 0 = Vy -> e1 (dPdy, Fy); contributes dVydy
    {
        const float* c = &sV[0][z][t4];
        const f4 ddt = dtv(c, cy, t4);
        const f4 ddz = d1v(c, z, S, T);
        const f4 lz  = d2cv(c, z, S, T);
        const float* g = V + vb;
        const f4 ddx = d1v(g, x, S, 2304);
        const f4 ddy = d1v(g, y, S, 110592);
        const f4 lx = xi ? (0.25f * (ld4(g - 4608)   + ld4(g + 4608))   - 0.5f * cy)
                         : d2cv(g, x, S, 2304);
        const f4 ly = yi ? (0.25f * (ld4(g - 221184) + ld4(g + 221184)) - 0.5f * cy)
                         : d2cv(g, y, S, 110592);
        const f4 dP = d1v(P + n4, y, S, 36864);
        const f4 e  = ddt + (cx * ddx + cy * ddy + cz * ddz + dP)
                      - re * (lz + lx + ly) + ld4(F + vb);
        sph += dot4(e * e);
        div = ddy;
    }
    // channel 1 = Vx -> e2 (dPdx, Fx); contributes dVxdx
    {
        const float* c = &sV[1][z][t4];
        const f4 ddt = dtv(c, cx, t4);
        const f4 ddz = d1v(c, z, S, T);
        const f4 lz  = d2cv(c, z, S, T);
        const float* g = V + vb + 16;
        const f4 ddx = d1v(g, x, S, 2304);
        const f4 ddy = d1v(g, y, S, 110592);
        const f4 lx = xi ? (0.25f * (ld4(g - 4608)   + ld4(g + 4608))   - 0.5f * cx)
                         : d2cv(g, x, S, 2304);
        const f4 ly = yi ? (0.25f * (ld4(g - 221184) + ld4(g + 221184)) - 0.5f * cx)
                         : d2cv(g, y, S, 110592);
        const f4 dP = d1v(P + n4, x, S, 768);
        const f4 e  = ddt + (cx * ddx + cy * ddy + cz * ddz + dP)
                      - re * (lz + lx + ly) + ld4(F + vb + 16);
        sph += dot4(e * e);
        div += ddx;
    }
    // channel 2 = Vz -> e3 (dPdz, Fz); contributes dVzdz
    {
        const float* c = &sV[2][z][t4];
        const f4 ddt = dtv(c, cz, t4);
        const f4 ddz = d1v(c, z, S, T);
        const f4 lz  = d2cv(c, z, S, T);
        const float* g = V + vb + 32;
        const f4 ddx = d1v(g, x, S, 2304);
        const f4 ddy = d1v(g, y, S, 110592);
        const f4 lx = xi ? (0.25f * (ld4(g - 4608)   + ld4(g + 4608))   - 0.5f * cz)
                         : d2cv(g, x, S, 2304);
        const f4 ly = yi ? (0.25f * (ld4(g - 221184) + ld4(g + 221184)) - 0.5f * cz)
                         : d2cv(g, y, S, 110592);
        const f4 dP = d1v(&sP[z][t4], z, S, T);   // z-derivative of P from LDS
        const f4 e  = ddt + (cx * ddx + cy * ddy + cz * ddz + dP)
                      - re * (lz + lx + ly) + ld4(F + vb + 32);
        sph += dot4(e * e);
        div += ddz;                               // e4 = dVxdx + dVydy + dVzdz
        sph += dot4(div * div);
    }

    // ---- reduction: wave shuffle -> LDS -> 5 atomics to a spread slot ----
    #pragma unroll
    for (int off = 32; off > 0; off >>= 1) {
        am1 += __shfl_down(am1, off);
        am2 += __shfl_down(am2, off);
        sph += __shfl_down(sph, off);
        at1 += __shfl_down(at1, off);
        at2 += __shfl_down(at2, off);
    }
    __shared__ float sred[3][5];
    const int lane = tid & 63;
    const int wv   = tid >> 6;
    if (lane == 0) {
        sred[wv][0] = am1; sred[wv][1] = am2; sred[wv][2] = sph;
        sred[wv][3] = at1; sred[wv][4] = at2;
    }
    __syncthreads();
    if (tid == 0) {
        float s0 = 0.f, s1 = 0.f, s2 = 0.f, s3 = 0.f, s4 = 0.f;
        #pragma unroll
        for (int w = 0; w < 3; ++w) {
            s0 += sred[w][0]; s1 += sred[w][1]; s2 += sred[w][2];
            s3 += sred[w][3]; s4 += sred[w][4];
        }
        float* slot = ws + (bidx & (NSLOT - 1)) * 16; // 64B apart
        atomicAdd(&slot[0], s0);
        atomicAdd(&slot[1], s1);
        atomicAdd(&slot[2], s2);
        atomicAdd(&slot[3], s3);
        atomicAdd(&slot[4], s4);
    }
}

// 64 threads: lane l sums slot l, then wave-shuffle combine.
__global__ void finalize_kernel(const float* __restrict__ ws, float* __restrict__ out) {
    const int l = threadIdx.x; // 0..63
    float s0 = ws[l * 16 + 0];
    float s1 = ws[l * 16 + 1];
    float s2 = ws[l * 16 + 2];
    float s3 = ws[l * 16 + 3];
    float s4 = ws[l * 16 + 4];
    #pragma unroll
    for (int off = 32; off > 0; off >>= 1) {
        s0 += __shfl_down(s0, off);
        s1 += __shfl_down(s1, off);
        s2 += __shfl_down(s2, off);
        s3 += __shfl_down(s3, off);
        s4 += __shfl_down(s4, off);
    }
    if (l == 0) {
        const float invN = 1.0f / (float)NTOT;
        const float m1  = s0 * invN;
        const float m2  = s1 * invN;
        const float phy = s2 * invN;
        const float t1  = s3 * invN;
        const float t2  = s4 * invN;
        out[0] = m1;
        out[1] = m2;
        out[2] = phy;
        out[3] = (t1 < t2) ? (t2 - t1) : 0.0f;
    }
}

extern "C" void kernel_launch(void* const* d_in, const int* in_sizes, int n_in,
                              void* d_out, int out_size, void* d_ws, size_t ws_size,
                              hipStream_t stream) {
    // setup_inputs order:
    // 0 C_all, 1 V_all, 2 P_all, 3 X_all, 4 X1_all, 5 F_all, 6 Re, 7 X_last,
    // 8 Y_data, 9 maskd0, 10 maskd1, 11 maskd2
    const float* Cmat  = (const float*)d_in[0];
    const float* V     = (const float*)d_in[1];
    const float* P     = (const float*)d_in[2];
    const float* Xa    = (const float*)d_in[3];
    const float* X1a   = (const float*)d_in[4];
    const float* F     = (const float*)d_in[5];
    const float* Rep   = (const float*)d_in[6];
    const float* Xlast = (const float*)d_in[7];
    const float* Y     = (const float*)d_in[8];

    float* ws  = (float*)d_ws;
    float* out = (float*)d_out;

    hipMemsetAsync(ws, 0, NSLOT * 16 * sizeof(float), stream); // 4 KB of slots
    fused_loss<<<NBLK, NTHR, 0, stream>>>(Cmat, V, P, Xa, X1a, F, Rep, Xlast, Y, ws);
    finalize_kernel<<<1, 64, 0, stream>>>(ws, out);
}